// Round 2
// baseline (5477.726 us; speedup 1.0000x reference)
//
#include <hip/hip_runtime.h>

// NConv depth-completion net, fp32 end-to-end. R2:
// - LDS holds interleaved float2(c, x*c) -> ds_read_b64, conflict-free
// - weights packed float4 over out-channels -> 1 b128 broadcast / tap
// - 2-row register blocking (16x32 tile per 256-thread block)
// - fused final 1x1 nconv + adaptive avg pool

#define EPSN 1e-20f

__device__ __forceinline__ float softplusf(float x) {
    // matches jax.nn.softplus = max(x,0) + log1p(exp(-|x|))
    return fmaxf(x, 0.f) + log1pf(expf(-fabsf(x)));
}
__device__ __forceinline__ float rcpf(float x) { return __builtin_amdgcn_rcpf(x); }

#define ACCUM(r, V)                                                        \
    acc[r][0].x = fmaf(w.x, (V).x, acc[r][0].x);                           \
    acc[r][0].y = fmaf(w.x, (V).y, acc[r][0].y);                           \
    acc[r][1].x = fmaf(w.y, (V).x, acc[r][1].x);                           \
    acc[r][1].y = fmaf(w.y, (V).y, acc[r][1].y);                           \
    acc[r][2].x = fmaf(w.z, (V).x, acc[r][2].x);                           \
    acc[r][2].y = fmaf(w.z, (V).y, acc[r][2].y);                           \
    acc[r][3].x = fmaf(w.w, (V).x, acc[r][3].x);                           \
    acc[r][3].y = fmaf(w.w, (V).y, acc[r][3].y);

// ---------------------------------------------------------------------------
// 5x5 normalized conv, pad=2, CO=4. CI=1 (FIRST: c0 = S>0.01 on the fly) or 4.
// 16x32 output tile, each thread computes 2 rows x 4 out-channels.
// ---------------------------------------------------------------------------
template<int CI, bool FIRST>
__global__ __launch_bounds__(256, 4) void nconv5(
    const float* __restrict__ xin, const float* __restrict__ cin,
    const float* __restrict__ wraw, const float* __restrict__ braw,
    float* __restrict__ xout, float* __restrict__ cout,
    int Hh, int Ww)
{
    const int LTH = 36, LTW = 20;                 // 32+4, 16+4
    __shared__ float2 sd[CI][LTH][LTW];           // (c, x*c)
    __shared__ float4 s_w4[CI * 25];              // weights packed over co
    __shared__ float4 s_sum, s_bias;

    const int b   = blockIdx.z;
    const int oh0 = blockIdx.y * 32, ow0 = blockIdx.x * 16;
    const int tid = threadIdx.y * 16 + threadIdx.x;

    if (tid < CI * 25) {
        float4 w;
        w.x = softplusf(wraw[0 * CI * 25 + tid]);
        w.y = softplusf(wraw[1 * CI * 25 + tid]);
        w.z = softplusf(wraw[2 * CI * 25 + tid]);
        w.w = softplusf(wraw[3 * CI * 25 + tid]);
        s_w4[tid] = w;
    }
    if (tid == 0) s_bias = make_float4(braw[0], braw[1], braw[2], braw[3]);
    __syncthreads();
    if (tid == 0) {
        float4 s = make_float4(0.f, 0.f, 0.f, 0.f);
        for (int i = 0; i < CI * 25; ++i) {
            float4 w = s_w4[i];
            s.x += w.x; s.y += w.y; s.z += w.z; s.w += w.w;
        }
        s_sum = s;
    }

    const size_t plane = (size_t)Hh * Ww;
    for (int i = tid; i < LTH * LTW; i += 256) {
        int ly = i / LTW, lx = i % LTW;
        int ih = oh0 - 2 + ly, iw = ow0 - 2 + lx;
        bool ok = (ih >= 0 && ih < Hh && iw >= 0 && iw < Ww);
        #pragma unroll
        for (int ci = 0; ci < CI; ++ci) {
            float x = 0.f, c = 0.f;
            if (ok) {
                size_t idx = ((size_t)(b * CI + ci)) * plane + (size_t)ih * Ww + iw;
                x = xin[idx];
                c = FIRST ? ((x > 0.01f) ? 1.f : 0.f) : cin[idx];
            }
            sd[ci][ly][lx] = make_float2(c, x * c);
        }
    }
    __syncthreads();

    const int ty = threadIdx.y, tx = threadIdx.x;
    float2 acc[2][4] = {};
    #pragma unroll
    for (int ci = 0; ci < CI; ++ci)
    #pragma unroll
    for (int kj = 0; kj < 5; ++kj)
    #pragma unroll
    for (int ki = 0; ki < 5; ++ki) {
        float2 v0 = sd[ci][ty + kj][tx + ki];
        float2 v1 = sd[ci][ty + 16 + kj][tx + ki];
        float4 w  = s_w4[ci * 25 + kj * 5 + ki];
        ACCUM(0, v0)
        ACCUM(1, v1)
    }

    const int ow = ow0 + tx;
    if (ow >= Ww) return;
    float4 bias = s_bias, ssum = s_sum;
    float rs0 = rcpf(ssum.x), rs1 = rcpf(ssum.y), rs2 = rcpf(ssum.z), rs3 = rcpf(ssum.w);
    #pragma unroll
    for (int r = 0; r < 2; ++r) {
        int oh = oh0 + ty + r * 16;
        if (oh >= Hh) continue;
        size_t ob = ((size_t)(b * 4)) * plane + (size_t)oh * Ww + ow;
        xout[ob + 0 * plane] = acc[r][0].y * rcpf(acc[r][0].x + EPSN) + bias.x;
        xout[ob + 1 * plane] = acc[r][1].y * rcpf(acc[r][1].x + EPSN) + bias.y;
        xout[ob + 2 * plane] = acc[r][2].y * rcpf(acc[r][2].x + EPSN) + bias.z;
        xout[ob + 3 * plane] = acc[r][3].y * rcpf(acc[r][3].x + EPSN) + bias.w;
        cout[ob + 0 * plane] = acc[r][0].x * rs0;
        cout[ob + 1 * plane] = acc[r][1].x * rs1;
        cout[ob + 2 * plane] = acc[r][2].x * rs2;
        cout[ob + 3 * plane] = acc[r][3].x * rs3;
    }
}

// ---------------------------------------------------------------------------
// 2x2 pool: argmax of confidence (first-max tie rule), gather x, c = max/4.
// ---------------------------------------------------------------------------
__global__ __launch_bounds__(256) void pool2k(
    const float* __restrict__ x, const float* __restrict__ c,
    float* __restrict__ xo, float* __restrict__ co, int Hh, int Ww)
{
    int H2 = Hh / 2, W2 = Ww / 2;
    int total = 8 * 4 * H2 * W2;
    int i = blockIdx.x * 256 + threadIdx.x;
    if (i >= total) return;
    int ow = i % W2;
    int oh = (i / W2) % H2;
    int ch = (i / (W2 * H2)) % 4;
    int b  =  i / (W2 * H2 * 4);
    size_t base = (((size_t)(b * 4 + ch)) * Hh + 2 * oh) * Ww + 2 * ow;
    float c00 = c[base], c01 = c[base + 1], c10 = c[base + Ww], c11 = c[base + Ww + 1];
    int k = 0; float cm = c00;
    if (c01 > cm) { cm = c01; k = 1; }
    if (c10 > cm) { cm = c10; k = 2; }
    if (c11 > cm) { cm = c11; k = 3; }
    float xv = (k == 0) ? x[base] : (k == 1) ? x[base + 1] : (k == 2) ? x[base + Ww] : x[base + Ww + 1];
    size_t ob = (((size_t)(b * 4 + ch)) * H2 + oh) * W2 + ow;
    xo[ob] = xv;
    co[ob] = cm * 0.25f;
}

// ---------------------------------------------------------------------------
// 3x3 normalized conv over concat of direct 4ch (Hin,Win) + nearest-2x-up
// 4ch (Hin/2,Win/2). UP_FIRST: upsampled in channels 0-3 (w6) else 4-7.
// 16x32 output tile, 2 rows/thread.
// ---------------------------------------------------------------------------
template<bool UP_FIRST, int PAD>
__global__ __launch_bounds__(256, 3) void nconv3cat(
    const float* __restrict__ xd, const float* __restrict__ cd,
    const float* __restrict__ xu, const float* __restrict__ cu,
    const float* __restrict__ wraw, const float* __restrict__ braw,
    float* __restrict__ xout, float* __restrict__ cout,
    int Hin, int Win)
{
    const int LTH = 34, LTW = 18;
    __shared__ float2 sd[8][LTH][LTW];
    __shared__ float4 s_w4[72];
    __shared__ float4 s_sum, s_bias;

    const int Hout = Hin - 2 + 2 * PAD, Wout = Win - 2 + 2 * PAD;
    const int b   = blockIdx.z;
    const int oh0 = blockIdx.y * 32, ow0 = blockIdx.x * 16;
    const int tid = threadIdx.y * 16 + threadIdx.x;

    if (tid < 72) {
        float4 w;
        w.x = softplusf(wraw[0 * 72 + tid]);
        w.y = softplusf(wraw[1 * 72 + tid]);
        w.z = softplusf(wraw[2 * 72 + tid]);
        w.w = softplusf(wraw[3 * 72 + tid]);
        s_w4[tid] = w;
    }
    if (tid == 0) s_bias = make_float4(braw[0], braw[1], braw[2], braw[3]);
    __syncthreads();
    if (tid == 0) {
        float4 s = make_float4(0.f, 0.f, 0.f, 0.f);
        for (int i = 0; i < 72; ++i) {
            float4 w = s_w4[i];
            s.x += w.x; s.y += w.y; s.z += w.z; s.w += w.w;
        }
        s_sum = s;
    }

    const int Hu = Hin / 2, Wu = Win / 2;
    const size_t planeD = (size_t)Hin * Win, planeU = (size_t)Hu * Wu;
    for (int i = tid; i < LTH * LTW; i += 256) {
        int ly = i / LTW, lx = i % LTW;
        int ih = oh0 - PAD + ly, iw = ow0 - PAD + lx;
        bool ok = (ih >= 0 && ih < Hin && iw >= 0 && iw < Win);
        #pragma unroll
        for (int ci = 0; ci < 4; ++ci) {
            float x = 0.f, c = 0.f;
            if (ok) {
                size_t idx = ((size_t)(b * 4 + ci)) * planeD + (size_t)ih * Win + iw;
                x = xd[idx]; c = cd[idx];
            }
            sd[UP_FIRST ? ci + 4 : ci][ly][lx] = make_float2(c, x * c);
        }
        #pragma unroll
        for (int ci = 0; ci < 4; ++ci) {
            float x = 0.f, c = 0.f;
            if (ok) {
                size_t idx = ((size_t)(b * 4 + ci)) * planeU + (size_t)(ih >> 1) * Wu + (iw >> 1);
                x = xu[idx]; c = cu[idx];
            }
            sd[UP_FIRST ? ci : ci + 4][ly][lx] = make_float2(c, x * c);
        }
    }
    __syncthreads();

    const int ty = threadIdx.y, tx = threadIdx.x;
    float2 acc[2][4] = {};
    #pragma unroll
    for (int ci = 0; ci < 8; ++ci)
    #pragma unroll
    for (int kj = 0; kj < 3; ++kj)
    #pragma unroll
    for (int ki = 0; ki < 3; ++ki) {
        float2 v0 = sd[ci][ty + kj][tx + ki];
        float2 v1 = sd[ci][ty + 16 + kj][tx + ki];
        float4 w  = s_w4[ci * 9 + kj * 3 + ki];
        ACCUM(0, v0)
        ACCUM(1, v1)
    }

    const int ow = ow0 + tx;
    if (ow >= Wout) return;
    float4 bias = s_bias, ssum = s_sum;
    float rs0 = rcpf(ssum.x), rs1 = rcpf(ssum.y), rs2 = rcpf(ssum.z), rs3 = rcpf(ssum.w);
    size_t planeO = (size_t)Hout * Wout;
    #pragma unroll
    for (int r = 0; r < 2; ++r) {
        int oh = oh0 + ty + r * 16;
        if (oh >= Hout) continue;
        size_t ob = ((size_t)(b * 4)) * planeO + (size_t)oh * Wout + ow;
        xout[ob + 0 * planeO] = acc[r][0].y * rcpf(acc[r][0].x + EPSN) + bias.x;
        xout[ob + 1 * planeO] = acc[r][1].y * rcpf(acc[r][1].x + EPSN) + bias.y;
        xout[ob + 2 * planeO] = acc[r][2].y * rcpf(acc[r][2].x + EPSN) + bias.z;
        xout[ob + 3 * planeO] = acc[r][3].y * rcpf(acc[r][3].x + EPSN) + bias.w;
        cout[ob + 0 * planeO] = acc[r][0].x * rs0;
        cout[ob + 1 * planeO] = acc[r][1].x * rs1;
        cout[ob + 2 * planeO] = acc[r][2].x * rs2;
        cout[ob + 3 * planeO] = acc[r][3].x * rs3;
    }
}

// ---------------------------------------------------------------------------
// 3x3 normalized conv, 4->4, pad=1 (w65). In-dims == out-dims (478x638).
// ---------------------------------------------------------------------------
__global__ __launch_bounds__(256, 4) void nconv3p(
    const float* __restrict__ xin, const float* __restrict__ cin,
    const float* __restrict__ wraw, const float* __restrict__ braw,
    float* __restrict__ xout, float* __restrict__ cout,
    int Hh, int Ww)
{
    const int LTH = 34, LTW = 18;
    __shared__ float2 sd[4][LTH][LTW];
    __shared__ float4 s_w4[36];
    __shared__ float4 s_sum, s_bias;

    const int b   = blockIdx.z;
    const int oh0 = blockIdx.y * 32, ow0 = blockIdx.x * 16;
    const int tid = threadIdx.y * 16 + threadIdx.x;

    if (tid < 36) {
        float4 w;
        w.x = softplusf(wraw[0 * 36 + tid]);
        w.y = softplusf(wraw[1 * 36 + tid]);
        w.z = softplusf(wraw[2 * 36 + tid]);
        w.w = softplusf(wraw[3 * 36 + tid]);
        s_w4[tid] = w;
    }
    if (tid == 0) s_bias = make_float4(braw[0], braw[1], braw[2], braw[3]);
    __syncthreads();
    if (tid == 0) {
        float4 s = make_float4(0.f, 0.f, 0.f, 0.f);
        for (int i = 0; i < 36; ++i) {
            float4 w = s_w4[i];
            s.x += w.x; s.y += w.y; s.z += w.z; s.w += w.w;
        }
        s_sum = s;
    }

    const size_t plane = (size_t)Hh * Ww;
    for (int i = tid; i < LTH * LTW; i += 256) {
        int ly = i / LTW, lx = i % LTW;
        int ih = oh0 - 1 + ly, iw = ow0 - 1 + lx;
        bool ok = (ih >= 0 && ih < Hh && iw >= 0 && iw < Ww);
        #pragma unroll
        for (int ci = 0; ci < 4; ++ci) {
            float x = 0.f, c = 0.f;
            if (ok) {
                size_t idx = ((size_t)(b * 4 + ci)) * plane + (size_t)ih * Ww + iw;
                x = xin[idx]; c = cin[idx];
            }
            sd[ci][ly][lx] = make_float2(c, x * c);
        }
    }
    __syncthreads();

    const int ty = threadIdx.y, tx = threadIdx.x;
    float2 acc[2][4] = {};
    #pragma unroll
    for (int ci = 0; ci < 4; ++ci)
    #pragma unroll
    for (int kj = 0; kj < 3; ++kj)
    #pragma unroll
    for (int ki = 0; ki < 3; ++ki) {
        float2 v0 = sd[ci][ty + kj][tx + ki];
        float2 v1 = sd[ci][ty + 16 + kj][tx + ki];
        float4 w  = s_w4[ci * 9 + kj * 3 + ki];
        ACCUM(0, v0)
        ACCUM(1, v1)
    }

    const int ow = ow0 + tx;
    if (ow >= Ww) return;
    float4 bias = s_bias, ssum = s_sum;
    float rs0 = rcpf(ssum.x), rs1 = rcpf(ssum.y), rs2 = rcpf(ssum.z), rs3 = rcpf(ssum.w);
    #pragma unroll
    for (int r = 0; r < 2; ++r) {
        int oh = oh0 + ty + r * 16;
        if (oh >= Hh) continue;
        size_t ob = ((size_t)(b * 4)) * plane + (size_t)oh * Ww + ow;
        xout[ob + 0 * plane] = acc[r][0].y * rcpf(acc[r][0].x + EPSN) + bias.x;
        xout[ob + 1 * plane] = acc[r][1].y * rcpf(acc[r][1].x + EPSN) + bias.y;
        xout[ob + 2 * plane] = acc[r][2].y * rcpf(acc[r][2].x + EPSN) + bias.z;
        xout[ob + 3 * plane] = acc[r][3].y * rcpf(acc[r][3].x + EPSN) + bias.w;
        cout[ob + 0 * plane] = acc[r][0].x * rs0;
        cout[ob + 1 * plane] = acc[r][1].x * rs1;
        cout[ob + 2 * plane] = acc[r][2].x * rs2;
        cout[ob + 3 * plane] = acc[r][3].x * rs3;
    }
}

// ---------------------------------------------------------------------------
// Fused: 1x1 nconv 4->1 (w7) on (478,638) + adaptive avg pool -> (480,640).
// ---------------------------------------------------------------------------
__global__ __launch_bounds__(256) void finalk(
    const float* __restrict__ x, const float* __restrict__ c,
    const float* __restrict__ w7, const float* __restrict__ b7,
    float* __restrict__ out)
{
    __shared__ float sw[5];
    if (threadIdx.x < 4) sw[threadIdx.x] = softplusf(w7[threadIdx.x]);
    if (threadIdx.x == 4) sw[4] = b7[0];
    __syncthreads();

    const int HI = 478, WI = 638, HO = 480, WO = 640;
    int total = 8 * HO * WO;
    int i = blockIdx.x * 256 + threadIdx.x;
    if (i >= total) return;
    int ow = i % WO;
    int oh = (i / WO) % HO;
    int b  = i / (WO * HO);
    float w0 = sw[0], w1 = sw[1], w2 = sw[2], w3 = sw[3], bias = sw[4];

    int sh = (oh * HI) / HO, eh = ((oh + 1) * HI + HO - 1) / HO;
    int sw_ = (ow * WI) / WO, ew = ((ow + 1) * WI + WO - 1) / WO;
    const size_t plane = (size_t)HI * WI;
    float s = 0.f;
    for (int ih = sh; ih < eh; ++ih)
        for (int iw = sw_; iw < ew; ++iw) {
            size_t base = (size_t)b * 4 * plane + (size_t)ih * WI + iw;
            float cc0 = c[base + 0 * plane], cc1 = c[base + 1 * plane],
                  cc2 = c[base + 2 * plane], cc3 = c[base + 3 * plane];
            float nom = w0 * x[base + 0 * plane] * cc0 + w1 * x[base + 1 * plane] * cc1
                      + w2 * x[base + 2 * plane] * cc2 + w3 * x[base + 3 * plane] * cc3;
            float den = w0 * cc0 + w1 * cc1 + w2 * cc2 + w3 * cc3;
            s += nom * rcpf(den + EPSN) + bias;
        }
    out[i] = s * rcpf((float)((eh - sh) * (ew - sw_)));
}

// ---------------------------------------------------------------------------
extern "C" void kernel_launch(void* const* d_in, const int* in_sizes, int n_in,
                              void* d_out, int out_size, void* d_ws, size_t ws_size,
                              hipStream_t stream)
{
    const float* S   = (const float*)d_in[1];
    const float* w1  = (const float*)d_in[3];  const float* b1  = (const float*)d_in[4];
    const float* w2  = (const float*)d_in[5];  const float* b2  = (const float*)d_in[6];
    const float* w3  = (const float*)d_in[7];  const float* b3  = (const float*)d_in[8];
    const float* w4  = (const float*)d_in[9];  const float* b4  = (const float*)d_in[10];
    const float* w5  = (const float*)d_in[11]; const float* b5  = (const float*)d_in[12];
    const float* w6  = (const float*)d_in[13]; const float* b6  = (const float*)d_in[14];
    const float* w65 = (const float*)d_in[15]; const float* b65 = (const float*)d_in[16];
    const float* w7  = (const float*)d_in[17]; const float* b7  = (const float*)d_in[18];
    float* out = (float*)d_out;
    float* ws  = (float*)d_ws;

    const size_t FULL = 9830400, HALF = 2457600, QUAR = 614400, EIGH = 153600;
    float *A0 = ws,        *A1 = A0 + FULL, *A2 = A1 + FULL, *A3 = A2 + FULL;
    float *P0 = A3 + FULL, *P1 = P0 + HALF, *P2 = P1 + HALF, *P3 = P2 + HALF;
    float *Q0 = P3 + HALF, *Q1 = Q0 + QUAR, *Q2 = Q1 + QUAR, *Q3 = Q2 + QUAR;
    float *E0 = Q3 + QUAR, *E1 = E0 + EIGH, *E2 = E1 + EIGH, *E3 = E2 + EIGH;

    dim3 blk(16, 16);
    auto grd = [](int Ho, int Wo) { return dim3((Wo + 15) / 16, (Ho + 31) / 32, 8); };

    // encoder, full res
    nconv5<1, true ><<<grd(480, 640), blk, 0, stream>>>(S,  S,  w1, b1, A0, A1, 480, 640);
    nconv5<4, false><<<grd(480, 640), blk, 0, stream>>>(A0, A1, w2, b2, A2, A3, 480, 640);
    nconv5<4, false><<<grd(480, 640), blk, 0, stream>>>(A2, A3, w3, b3, A0, A1, 480, 640);
    // 1/2 scale
    pool2k<<<(8 * 4 * 240 * 320 + 255) / 256, 256, 0, stream>>>(A0, A1, P0, P1, 480, 640);
    nconv5<4, false><<<grd(240, 320), blk, 0, stream>>>(P0, P1, w2, b2, P2, P3, 240, 320);
    nconv5<4, false><<<grd(240, 320), blk, 0, stream>>>(P2, P3, w3, b3, P0, P1, 240, 320); // x2_ds
    // 1/4 scale
    pool2k<<<(8 * 4 * 120 * 160 + 255) / 256, 256, 0, stream>>>(P0, P1, Q0, Q1, 240, 320);
    nconv5<4, false><<<grd(120, 160), blk, 0, stream>>>(Q0, Q1, w2, b2, Q2, Q3, 120, 160); // x3_ds
    // 1/8 scale
    pool2k<<<(8 * 4 * 60 * 80 + 255) / 256, 256, 0, stream>>>(Q2, Q3, E0, E1, 120, 160);
    nconv5<4, false><<<grd(60, 80), blk, 0, stream>>>(E0, E1, w2, b2, E2, E3, 60, 80);     // x4_ds
    // decoder
    nconv3cat<false, 1><<<grd(120, 160), blk, 0, stream>>>(Q2, Q3, E2, E3, w4, b4, Q0, Q1, 120, 160);
    nconv3cat<false, 1><<<grd(240, 320), blk, 0, stream>>>(P0, P1, Q0, Q1, w5, b5, P2, P3, 240, 320);
    nconv3cat<true , 0><<<grd(478, 638), blk, 0, stream>>>(A0, A1, P2, P3, w6, b6, A2, A3, 480, 640);
    nconv3p<<<grd(478, 638), blk, 0, stream>>>(A2, A3, w65, b65, A0, A1, 478, 638);
    finalk<<<(8 * 480 * 640 + 255) / 256, 256, 0, stream>>>(A0, A1, w7, b7, out);
}

// Round 3
// 648.110 us; speedup vs baseline: 8.4518x; 8.4518x over previous
//
#include <hip/hip_runtime.h>

// NConv depth-completion net, fp32 end-to-end. R3:
// R1 structure (known-good coalescing) + float4-packed weights (1 b128
// broadcast per tap), v_rcp_f32, fused final 1x1 nconv + adaptive pool.
// R2's {float2 LDS staging, 2-row blocking, launch_bounds minwaves} reverted —
// R2 showed per-lane 128-B HBM transactions (32x write amplification).

#define EPSN 1e-20f

__device__ __forceinline__ float softplusf(float x) {
    // matches jax.nn.softplus = max(x,0) + log1p(exp(-|x|))
    return fmaxf(x, 0.f) + log1pf(expf(-fabsf(x)));
}
__device__ __forceinline__ float rcpf(float x) { return __builtin_amdgcn_rcpf(x); }

// ---------------------------------------------------------------------------
// 5x5 normalized conv, pad=2, CO=4. CI=1 (FIRST: c0 = S>0.01 on the fly) or 4.
// One thread per output pixel, all 4 out channels. 16x16 tile + halo 2 in LDS.
// ---------------------------------------------------------------------------
template<int CI, bool FIRST>
__global__ __launch_bounds__(256) void nconv5(
    const float* __restrict__ xin, const float* __restrict__ cin,
    const float* __restrict__ wraw, const float* __restrict__ braw,
    float* __restrict__ xout, float* __restrict__ cout,
    int Hh, int Ww)
{
    const int TS = 16, HALO = 2, LT = TS + 2 * HALO;   // 20
    __shared__ float s_c [CI][LT][LT + 1];
    __shared__ float s_xc[CI][LT][LT + 1];
    __shared__ float4 s_w4[CI * 25];                   // packed over out-ch
    __shared__ float4 s_sum, s_bias;

    const int b   = blockIdx.z;
    const int oh0 = blockIdx.y * TS, ow0 = blockIdx.x * TS;
    const int tid = threadIdx.y * 16 + threadIdx.x;

    if (tid < CI * 25) {
        float4 w;
        w.x = softplusf(wraw[0 * CI * 25 + tid]);
        w.y = softplusf(wraw[1 * CI * 25 + tid]);
        w.z = softplusf(wraw[2 * CI * 25 + tid]);
        w.w = softplusf(wraw[3 * CI * 25 + tid]);
        s_w4[tid] = w;
    }
    if (tid == 0) s_bias = make_float4(braw[0], braw[1], braw[2], braw[3]);
    __syncthreads();
    if (tid == 0) {
        float4 s = make_float4(0.f, 0.f, 0.f, 0.f);
        for (int i = 0; i < CI * 25; ++i) {
            float4 w = s_w4[i];
            s.x += w.x; s.y += w.y; s.z += w.z; s.w += w.w;
        }
        s_sum = s;
    }

    const size_t plane = (size_t)Hh * Ww;
    for (int i = tid; i < LT * LT; i += 256) {
        int ly = i / LT, lx = i % LT;
        int ih = oh0 - HALO + ly, iw = ow0 - HALO + lx;
        bool ok = (ih >= 0 && ih < Hh && iw >= 0 && iw < Ww);
        #pragma unroll
        for (int ci = 0; ci < CI; ++ci) {
            float x = 0.f, c = 0.f;
            if (ok) {
                size_t idx = ((size_t)(b * CI + ci)) * plane + (size_t)ih * Ww + iw;
                x = xin[idx];
                if (FIRST) c = (x > 0.01f) ? 1.f : 0.f;
                else       c = cin[idx];
            }
            s_c [ci][ly][lx] = c;
            s_xc[ci][ly][lx] = x * c;
        }
    }
    __syncthreads();

    const int oh = oh0 + threadIdx.y, ow = ow0 + threadIdx.x;
    if (oh >= Hh || ow >= Ww) return;

    float nom[4] = {0.f, 0.f, 0.f, 0.f}, den[4] = {0.f, 0.f, 0.f, 0.f};
    #pragma unroll
    for (int ci = 0; ci < CI; ++ci)
    #pragma unroll
    for (int kj = 0; kj < 5; ++kj)
    #pragma unroll
    for (int ki = 0; ki < 5; ++ki) {
        float c  = s_c [ci][threadIdx.y + kj][threadIdx.x + ki];
        float xc = s_xc[ci][threadIdx.y + kj][threadIdx.x + ki];
        float4 w = s_w4[ci * 25 + kj * 5 + ki];
        nom[0] = fmaf(w.x, xc, nom[0]); den[0] = fmaf(w.x, c, den[0]);
        nom[1] = fmaf(w.y, xc, nom[1]); den[1] = fmaf(w.y, c, den[1]);
        nom[2] = fmaf(w.z, xc, nom[2]); den[2] = fmaf(w.z, c, den[2]);
        nom[3] = fmaf(w.w, xc, nom[3]); den[3] = fmaf(w.w, c, den[3]);
    }
    float4 bias = s_bias, ssum = s_sum;
    size_t ob = ((size_t)(b * 4)) * plane + (size_t)oh * Ww + ow;
    xout[ob + 0 * plane] = nom[0] * rcpf(den[0] + EPSN) + bias.x;
    xout[ob + 1 * plane] = nom[1] * rcpf(den[1] + EPSN) + bias.y;
    xout[ob + 2 * plane] = nom[2] * rcpf(den[2] + EPSN) + bias.z;
    xout[ob + 3 * plane] = nom[3] * rcpf(den[3] + EPSN) + bias.w;
    cout[ob + 0 * plane] = den[0] * rcpf(ssum.x);
    cout[ob + 1 * plane] = den[1] * rcpf(ssum.y);
    cout[ob + 2 * plane] = den[2] * rcpf(ssum.z);
    cout[ob + 3 * plane] = den[3] * rcpf(ssum.w);
}

// ---------------------------------------------------------------------------
// 2x2 pool: argmax of confidence (first-max tie rule), gather x, c = max/4.
// ---------------------------------------------------------------------------
__global__ __launch_bounds__(256) void pool2k(
    const float* __restrict__ x, const float* __restrict__ c,
    float* __restrict__ xo, float* __restrict__ co, int Hh, int Ww)
{
    int H2 = Hh / 2, W2 = Ww / 2;
    int total = 8 * 4 * H2 * W2;
    int i = blockIdx.x * 256 + threadIdx.x;
    if (i >= total) return;
    int ow = i % W2;
    int oh = (i / W2) % H2;
    int ch = (i / (W2 * H2)) % 4;
    int b  =  i / (W2 * H2 * 4);
    size_t base = (((size_t)(b * 4 + ch)) * Hh + 2 * oh) * Ww + 2 * ow;
    float c00 = c[base], c01 = c[base + 1], c10 = c[base + Ww], c11 = c[base + Ww + 1];
    int k = 0; float cm = c00;
    if (c01 > cm) { cm = c01; k = 1; }
    if (c10 > cm) { cm = c10; k = 2; }
    if (c11 > cm) { cm = c11; k = 3; }
    float xv = (k == 0) ? x[base] : (k == 1) ? x[base + 1] : (k == 2) ? x[base + Ww] : x[base + Ww + 1];
    size_t ob = (((size_t)(b * 4 + ch)) * H2 + oh) * W2 + ow;
    xo[ob] = xv;
    co[ob] = cm * 0.25f;
}

// ---------------------------------------------------------------------------
// 3x3 normalized conv over concat of direct 4ch (Hin,Win) + nearest-2x-up
// 4ch (Hin/2,Win/2). UP_FIRST: upsampled in channels 0-3 (w6) else 4-7.
// ---------------------------------------------------------------------------
template<bool UP_FIRST, int PAD>
__global__ __launch_bounds__(256) void nconv3cat(
    const float* __restrict__ xd, const float* __restrict__ cd,
    const float* __restrict__ xu, const float* __restrict__ cu,
    const float* __restrict__ wraw, const float* __restrict__ braw,
    float* __restrict__ xout, float* __restrict__ cout,
    int Hin, int Win)
{
    const int TS = 16, LT = TS + 2;   // 18
    __shared__ float s_c [8][LT][LT + 1];
    __shared__ float s_xc[8][LT][LT + 1];
    __shared__ float4 s_w4[72];
    __shared__ float4 s_sum, s_bias;

    const int Hout = Hin - 2 + 2 * PAD, Wout = Win - 2 + 2 * PAD;
    const int b   = blockIdx.z;
    const int oh0 = blockIdx.y * TS, ow0 = blockIdx.x * TS;
    const int tid = threadIdx.y * 16 + threadIdx.x;

    if (tid < 72) {
        float4 w;
        w.x = softplusf(wraw[0 * 72 + tid]);
        w.y = softplusf(wraw[1 * 72 + tid]);
        w.z = softplusf(wraw[2 * 72 + tid]);
        w.w = softplusf(wraw[3 * 72 + tid]);
        s_w4[tid] = w;
    }
    if (tid == 0) s_bias = make_float4(braw[0], braw[1], braw[2], braw[3]);
    __syncthreads();
    if (tid == 0) {
        float4 s = make_float4(0.f, 0.f, 0.f, 0.f);
        for (int i = 0; i < 72; ++i) {
            float4 w = s_w4[i];
            s.x += w.x; s.y += w.y; s.z += w.z; s.w += w.w;
        }
        s_sum = s;
    }

    const int Hu = Hin / 2, Wu = Win / 2;
    const size_t planeD = (size_t)Hin * Win, planeU = (size_t)Hu * Wu;
    for (int i = tid; i < LT * LT; i += 256) {
        int ly = i / LT, lx = i % LT;
        int ih = oh0 - PAD + ly, iw = ow0 - PAD + lx;
        bool ok = (ih >= 0 && ih < Hin && iw >= 0 && iw < Win);
        #pragma unroll
        for (int ci = 0; ci < 4; ++ci) {
            float x = 0.f, c = 0.f;
            if (ok) {
                size_t idx = ((size_t)(b * 4 + ci)) * planeD + (size_t)ih * Win + iw;
                x = xd[idx]; c = cd[idx];
            }
            int ch = UP_FIRST ? ci + 4 : ci;
            s_c [ch][ly][lx] = c;
            s_xc[ch][ly][lx] = x * c;
        }
        #pragma unroll
        for (int ci = 0; ci < 4; ++ci) {
            float x = 0.f, c = 0.f;
            if (ok) {
                size_t idx = ((size_t)(b * 4 + ci)) * planeU + (size_t)(ih >> 1) * Wu + (iw >> 1);
                x = xu[idx]; c = cu[idx];
            }
            int ch = UP_FIRST ? ci : ci + 4;
            s_c [ch][ly][lx] = c;
            s_xc[ch][ly][lx] = x * c;
        }
    }
    __syncthreads();

    const int oh = oh0 + threadIdx.y, ow = ow0 + threadIdx.x;
    if (oh >= Hout || ow >= Wout) return;

    float nom[4] = {0.f, 0.f, 0.f, 0.f}, den[4] = {0.f, 0.f, 0.f, 0.f};
    #pragma unroll
    for (int ci = 0; ci < 8; ++ci)
    #pragma unroll
    for (int kj = 0; kj < 3; ++kj)
    #pragma unroll
    for (int ki = 0; ki < 3; ++ki) {
        float c  = s_c [ci][threadIdx.y + kj][threadIdx.x + ki];
        float xc = s_xc[ci][threadIdx.y + kj][threadIdx.x + ki];
        float4 w = s_w4[ci * 9 + kj * 3 + ki];
        nom[0] = fmaf(w.x, xc, nom[0]); den[0] = fmaf(w.x, c, den[0]);
        nom[1] = fmaf(w.y, xc, nom[1]); den[1] = fmaf(w.y, c, den[1]);
        nom[2] = fmaf(w.z, xc, nom[2]); den[2] = fmaf(w.z, c, den[2]);
        nom[3] = fmaf(w.w, xc, nom[3]); den[3] = fmaf(w.w, c, den[3]);
    }
    float4 bias = s_bias, ssum = s_sum;
    size_t planeO = (size_t)Hout * Wout;
    size_t ob = ((size_t)(b * 4)) * planeO + (size_t)oh * Wout + ow;
    xout[ob + 0 * planeO] = nom[0] * rcpf(den[0] + EPSN) + bias.x;
    xout[ob + 1 * planeO] = nom[1] * rcpf(den[1] + EPSN) + bias.y;
    xout[ob + 2 * planeO] = nom[2] * rcpf(den[2] + EPSN) + bias.z;
    xout[ob + 3 * planeO] = nom[3] * rcpf(den[3] + EPSN) + bias.w;
    cout[ob + 0 * planeO] = den[0] * rcpf(ssum.x);
    cout[ob + 1 * planeO] = den[1] * rcpf(ssum.y);
    cout[ob + 2 * planeO] = den[2] * rcpf(ssum.z);
    cout[ob + 3 * planeO] = den[3] * rcpf(ssum.w);
}

// ---------------------------------------------------------------------------
// 3x3 normalized conv, 4->4, pad=1 (w65). In-dims == out-dims (478x638).
// ---------------------------------------------------------------------------
__global__ __launch_bounds__(256) void nconv3p(
    const float* __restrict__ xin, const float* __restrict__ cin,
    const float* __restrict__ wraw, const float* __restrict__ braw,
    float* __restrict__ xout, float* __restrict__ cout,
    int Hh, int Ww)
{
    const int TS = 16, LT = TS + 2;
    __shared__ float s_c [4][LT][LT + 1];
    __shared__ float s_xc[4][LT][LT + 1];
    __shared__ float4 s_w4[36];
    __shared__ float4 s_sum, s_bias;

    const int b   = blockIdx.z;
    const int oh0 = blockIdx.y * TS, ow0 = blockIdx.x * TS;
    const int tid = threadIdx.y * 16 + threadIdx.x;

    if (tid < 36) {
        float4 w;
        w.x = softplusf(wraw[0 * 36 + tid]);
        w.y = softplusf(wraw[1 * 36 + tid]);
        w.z = softplusf(wraw[2 * 36 + tid]);
        w.w = softplusf(wraw[3 * 36 + tid]);
        s_w4[tid] = w;
    }
    if (tid == 0) s_bias = make_float4(braw[0], braw[1], braw[2], braw[3]);
    __syncthreads();
    if (tid == 0) {
        float4 s = make_float4(0.f, 0.f, 0.f, 0.f);
        for (int i = 0; i < 36; ++i) {
            float4 w = s_w4[i];
            s.x += w.x; s.y += w.y; s.z += w.z; s.w += w.w;
        }
        s_sum = s;
    }

    const size_t plane = (size_t)Hh * Ww;
    for (int i = tid; i < LT * LT; i += 256) {
        int ly = i / LT, lx = i % LT;
        int ih = oh0 - 1 + ly, iw = ow0 - 1 + lx;
        bool ok = (ih >= 0 && ih < Hh && iw >= 0 && iw < Ww);
        #pragma unroll
        for (int ci = 0; ci < 4; ++ci) {
            float x = 0.f, c = 0.f;
            if (ok) {
                size_t idx = ((size_t)(b * 4 + ci)) * plane + (size_t)ih * Ww + iw;
                x = xin[idx]; c = cin[idx];
            }
            s_c [ci][ly][lx] = c;
            s_xc[ci][ly][lx] = x * c;
        }
    }
    __syncthreads();

    const int oh = oh0 + threadIdx.y, ow = ow0 + threadIdx.x;
    if (oh >= Hh || ow >= Ww) return;

    float nom[4] = {0.f, 0.f, 0.f, 0.f}, den[4] = {0.f, 0.f, 0.f, 0.f};
    #pragma unroll
    for (int ci = 0; ci < 4; ++ci)
    #pragma unroll
    for (int kj = 0; kj < 3; ++kj)
    #pragma unroll
    for (int ki = 0; ki < 3; ++ki) {
        float c  = s_c [ci][threadIdx.y + kj][threadIdx.x + ki];
        float xc = s_xc[ci][threadIdx.y + kj][threadIdx.x + ki];
        float4 w = s_w4[ci * 9 + kj * 3 + ki];
        nom[0] = fmaf(w.x, xc, nom[0]); den[0] = fmaf(w.x, c, den[0]);
        nom[1] = fmaf(w.y, xc, nom[1]); den[1] = fmaf(w.y, c, den[1]);
        nom[2] = fmaf(w.z, xc, nom[2]); den[2] = fmaf(w.z, c, den[2]);
        nom[3] = fmaf(w.w, xc, nom[3]); den[3] = fmaf(w.w, c, den[3]);
    }
    float4 bias = s_bias, ssum = s_sum;
    size_t ob = ((size_t)(b * 4)) * plane + (size_t)oh * Ww + ow;
    xout[ob + 0 * plane] = nom[0] * rcpf(den[0] + EPSN) + bias.x;
    xout[ob + 1 * plane] = nom[1] * rcpf(den[1] + EPSN) + bias.y;
    xout[ob + 2 * plane] = nom[2] * rcpf(den[2] + EPSN) + bias.z;
    xout[ob + 3 * plane] = nom[3] * rcpf(den[3] + EPSN) + bias.w;
    cout[ob + 0 * plane] = den[0] * rcpf(ssum.x);
    cout[ob + 1 * plane] = den[1] * rcpf(ssum.y);
    cout[ob + 2 * plane] = den[2] * rcpf(ssum.z);
    cout[ob + 3 * plane] = den[3] * rcpf(ssum.w);
}

// ---------------------------------------------------------------------------
// Fused: 1x1 nconv 4->1 (w7) on (478,638) + adaptive avg pool -> (480,640).
// ---------------------------------------------------------------------------
__global__ __launch_bounds__(256) void finalk(
    const float* __restrict__ x, const float* __restrict__ c,
    const float* __restrict__ w7, const float* __restrict__ b7,
    float* __restrict__ out)
{
    __shared__ float sw[5];
    if (threadIdx.x < 4) sw[threadIdx.x] = softplusf(w7[threadIdx.x]);
    if (threadIdx.x == 4) sw[4] = b7[0];
    __syncthreads();

    const int HI = 478, WI = 638, HO = 480, WO = 640;
    int total = 8 * HO * WO;
    int i = blockIdx.x * 256 + threadIdx.x;
    if (i >= total) return;
    int ow = i % WO;
    int oh = (i / WO) % HO;
    int b  = i / (WO * HO);
    float w0 = sw[0], w1 = sw[1], w2 = sw[2], w3 = sw[3], bias = sw[4];

    int sh = (oh * HI) / HO, eh = ((oh + 1) * HI + HO - 1) / HO;
    int sw_ = (ow * WI) / WO, ew = ((ow + 1) * WI + WO - 1) / WO;
    const size_t plane = (size_t)HI * WI;
    float s = 0.f;
    for (int ih = sh; ih < eh; ++ih)
        for (int iw = sw_; iw < ew; ++iw) {
            size_t base = (size_t)b * 4 * plane + (size_t)ih * WI + iw;
            float cc0 = c[base + 0 * plane], cc1 = c[base + 1 * plane],
                  cc2 = c[base + 2 * plane], cc3 = c[base + 3 * plane];
            float nom = w0 * x[base + 0 * plane] * cc0 + w1 * x[base + 1 * plane] * cc1
                      + w2 * x[base + 2 * plane] * cc2 + w3 * x[base + 3 * plane] * cc3;
            float den = w0 * cc0 + w1 * cc1 + w2 * cc2 + w3 * cc3;
            s += nom * rcpf(den + EPSN) + bias;
        }
    out[i] = s * rcpf((float)((eh - sh) * (ew - sw_)));
}

// ---------------------------------------------------------------------------
extern "C" void kernel_launch(void* const* d_in, const int* in_sizes, int n_in,
                              void* d_out, int out_size, void* d_ws, size_t ws_size,
                              hipStream_t stream)
{
    const float* S   = (const float*)d_in[1];
    const float* w1  = (const float*)d_in[3];  const float* b1  = (const float*)d_in[4];
    const float* w2  = (const float*)d_in[5];  const float* b2  = (const float*)d_in[6];
    const float* w3  = (const float*)d_in[7];  const float* b3  = (const float*)d_in[8];
    const float* w4  = (const float*)d_in[9];  const float* b4  = (const float*)d_in[10];
    const float* w5  = (const float*)d_in[11]; const float* b5  = (const float*)d_in[12];
    const float* w6  = (const float*)d_in[13]; const float* b6  = (const float*)d_in[14];
    const float* w65 = (const float*)d_in[15]; const float* b65 = (const float*)d_in[16];
    const float* w7  = (const float*)d_in[17]; const float* b7  = (const float*)d_in[18];
    float* out = (float*)d_out;
    float* ws  = (float*)d_ws;

    const size_t FULL = 9830400, HALF = 2457600, QUAR = 614400, EIGH = 153600;
    float *A0 = ws,        *A1 = A0 + FULL, *A2 = A1 + FULL, *A3 = A2 + FULL;
    float *P0 = A3 + FULL, *P1 = P0 + HALF, *P2 = P1 + HALF, *P3 = P2 + HALF;
    float *Q0 = P3 + HALF, *Q1 = Q0 + QUAR, *Q2 = Q1 + QUAR, *Q3 = Q2 + QUAR;
    float *E0 = Q3 + QUAR, *E1 = E0 + EIGH, *E2 = E1 + EIGH, *E3 = E2 + EIGH;

    dim3 blk(16, 16);
    auto grd = [](int Ho, int Wo) { return dim3((Wo + 15) / 16, (Ho + 15) / 16, 8); };

    // encoder, full res
    nconv5<1, true ><<<grd(480, 640), blk, 0, stream>>>(S,  S,  w1, b1, A0, A1, 480, 640);
    nconv5<4, false><<<grd(480, 640), blk, 0, stream>>>(A0, A1, w2, b2, A2, A3, 480, 640);
    nconv5<4, false><<<grd(480, 640), blk, 0, stream>>>(A2, A3, w3, b3, A0, A1, 480, 640);
    // 1/2 scale
    pool2k<<<(8 * 4 * 240 * 320 + 255) / 256, 256, 0, stream>>>(A0, A1, P0, P1, 480, 640);
    nconv5<4, false><<<grd(240, 320), blk, 0, stream>>>(P0, P1, w2, b2, P2, P3, 240, 320);
    nconv5<4, false><<<grd(240, 320), blk, 0, stream>>>(P2, P3, w3, b3, P0, P1, 240, 320); // x2_ds
    // 1/4 scale
    pool2k<<<(8 * 4 * 120 * 160 + 255) / 256, 256, 0, stream>>>(P0, P1, Q0, Q1, 240, 320);
    nconv5<4, false><<<grd(120, 160), blk, 0, stream>>>(Q0, Q1, w2, b2, Q2, Q3, 120, 160); // x3_ds
    // 1/8 scale
    pool2k<<<(8 * 4 * 60 * 80 + 255) / 256, 256, 0, stream>>>(Q2, Q3, E0, E1, 120, 160);
    nconv5<4, false><<<grd(60, 80), blk, 0, stream>>>(E0, E1, w2, b2, E2, E3, 60, 80);     // x4_ds
    // decoder
    nconv3cat<false, 1><<<grd(120, 160), blk, 0, stream>>>(Q2, Q3, E2, E3, w4, b4, Q0, Q1, 120, 160);
    nconv3cat<false, 1><<<grd(240, 320), blk, 0, stream>>>(P0, P1, Q0, Q1, w5, b5, P2, P3, 240, 320);
    nconv3cat<true , 0><<<grd(478, 638), blk, 0, stream>>>(A0, A1, P2, P3, w6, b6, A2, A3, 480, 640);
    nconv3p<<<grd(478, 638), blk, 0, stream>>>(A2, A3, w65, b65, A0, A1, 478, 638);
    finalk<<<(8 * 480 * 640 + 255) / 256, 256, 0, stream>>>(A0, A1, w7, b7, out);
}